// Round 3
// baseline (368.057 us; speedup 1.0000x reference)
//
#include <hip/hip_runtime.h>

typedef unsigned short u16;
typedef __attribute__((ext_vector_type(8)))  short bf16x8;
typedef __attribute__((ext_vector_type(16))) float f32x16;

#define NROWS 131072
#define NMOL  2048
#define CIN   128
#define HDIM  1024
#define BM    64
#define EMBSTRIDE 1152   // 9*128

#define KT1 (CIN  / 16)   // 8
#define KT2 (HDIM / 16)   // 64
#define NT  (HDIM / 32)   // 32

// ---------- helpers ----------
__device__ __forceinline__ u16 f2bf(float f) {
    union { float f; unsigned u; } v; v.f = f;
    unsigned u = v.u;
    u += 0x7FFFu + ((u >> 16) & 1u);   // round-to-nearest-even
    return (u16)(u >> 16);
}

__device__ __forceinline__ float silu_f(float v) {
    float e = __expf(-v);
    return v * __builtin_amdgcn_rcpf(1.0f + e);
}

__device__ __forceinline__ f32x16 mfma32(bf16x8 a, bf16x8 b, f32x16 c) {
    return __builtin_amdgcn_mfma_f32_32x32x16_bf16(a, b, c, 0, 0, 0);
}

// ---------- pre-pass: pack W (K x N fp32 row-major) into bf16 32x32x16 B-fragments ----------
// frag id = kt*NT + nt. lane l, elem j -> W[kt*16 + (l>>5)*8 + j][nt*32 + (l&31)]
__global__ void pack_w32(const float* __restrict__ W, u16* __restrict__ dst, int K, int N) {
    int tid  = blockIdx.x * blockDim.x + threadIdx.x;
    int lane = tid & 63;
    int frag = tid >> 6;
    int NTl = N >> 5;
    int KTl = K >> 4;
    if (frag >= KTl * NTl) return;
    int kt = frag / NTl;
    int nt = frag - kt * NTl;
    int col  = (nt << 5) + (lane & 31);
    int krow = (kt << 4) + ((lane >> 5) << 3);
    __align__(16) u16 tmp[8];
    #pragma unroll
    for (int j = 0; j < 8; ++j) tmp[j] = f2bf(W[(size_t)(krow + j) * N + col]);
    *reinterpret_cast<uint4*>(dst + (size_t)tid * 8) = *reinterpret_cast<uint4*>(tmp);
}

// ---------- fused MLP : 1024 threads = 16 waves, 4 waves/SIMD ----------
// wave w covers output cols [w*64, w*64+64) = nt {2w, 2w+1}; all 64 rows (2 mt strips).
__global__ __launch_bounds__(1024, 4) void fused_mlp(
    const float* __restrict__ emb,
    const u16*  __restrict__ w1f,
    const u16*  __restrict__ w2f,
    const float* __restrict__ b1,
    const float* __restrict__ b2,
    const float* __restrict__ w3,
    const float* __restrict__ b3,
    float* __restrict__ node_e)
{
    __shared__ u16  x_lds[BM][CIN + 8];      // 64 x 136 bf16 : 17.4 KB
    __shared__ u16  h1_lds[BM][HDIM + 8];    // 64 x 1032 bf16: 132 KB
    __shared__ float e_red[16][BM];          // 4 KB

    const int tid  = threadIdx.x;
    const int lane = tid & 63;
    const int w    = tid >> 6;               // wave 0..15
    const int l31  = lane & 31;
    const int lhi  = lane >> 5;              // 0/1
    const int row0 = blockIdx.x * BM;

    // ---- phase 0: stage x tile as bf16 (1024 threads: 64 rows x 16 segs of 8 floats) ----
    {
        int r   = tid >> 4;                  // 0..63
        int seg = tid & 15;                  // 16 segs of 8 floats
        const float4* s4 = reinterpret_cast<const float4*>(
            emb + (size_t)(row0 + r) * EMBSTRIDE + seg * 8);
        float4 f0 = s4[0], f1 = s4[1];
        __align__(16) u16 u[8];
        u[0] = f2bf(f0.x); u[1] = f2bf(f0.y); u[2] = f2bf(f0.z); u[3] = f2bf(f0.w);
        u[4] = f2bf(f1.x); u[5] = f2bf(f1.y); u[6] = f2bf(f1.z); u[7] = f2bf(f1.w);
        *reinterpret_cast<uint4*>(&x_lds[r][seg * 8]) = *reinterpret_cast<uint4*>(u);
    }

    // B-fragment loaders: nt = 2w + nti, nti in {0,1}
    auto LDB1 = [&](int kt, bf16x8* b) {
        #pragma unroll
        for (int nti = 0; nti < 2; ++nti)
            b[nti] = *reinterpret_cast<const bf16x8*>(
                w1f + (((size_t)kt * NT + 2 * w + nti) * 64 + lane) * 8);
    };
    auto LDB2 = [&](int kt, bf16x8* b) {
        #pragma unroll
        for (int nti = 0; nti < 2; ++nti)
            b[nti] = *reinterpret_cast<const bf16x8*>(
                w2f + (((size_t)kt * NT + 2 * w + nti) * 64 + lane) * 8);
    };

    bf16x8 bC[2], bN[2];
    LDB1(0, bC);
    LDB1(1, bN);
    __syncthreads();

    // ---- phase 1: h1 = silu(x @ W1 + b1) ----
    {
        f32x16 acc1[2][2];
        #pragma unroll
        for (int mt = 0; mt < 2; ++mt)
            #pragma unroll
            for (int nti = 0; nti < 2; ++nti)
                #pragma unroll
                for (int r = 0; r < 16; ++r) acc1[mt][nti][r] = 0.0f;

        #pragma unroll
        for (int kt = 0; kt < KT1; ++kt) {
            bf16x8 a[2];
            #pragma unroll
            for (int mt = 0; mt < 2; ++mt)
                a[mt] = *reinterpret_cast<const bf16x8*>(
                    &x_lds[mt*32 + l31][kt*16 + (lhi << 3)]);
            bf16x8 bP[2];
            if (kt + 2 < KT1) LDB1(kt + 2, bP);
            #pragma unroll
            for (int nti = 0; nti < 2; ++nti)
                #pragma unroll
                for (int mt = 0; mt < 2; ++mt)
                    acc1[mt][nti] = mfma32(a[mt], bC[nti], acc1[mt][nti]);
            #pragma unroll
            for (int i = 0; i < 2; ++i) { bC[i] = bN[i]; bN[i] = bP[i]; }
        }

        // epilogue: silu -> bf16 -> h1_lds  (C/D: col=lane&31, row=(r&3)+8*(r>>2)+4*lhi)
        #pragma unroll
        for (int nti = 0; nti < 2; ++nti) {
            int col = w*64 + nti*32 + l31;
            float bias = b1[col];
            #pragma unroll
            for (int mt = 0; mt < 2; ++mt)
                #pragma unroll
                for (int r = 0; r < 16; ++r) {
                    int row = mt*32 + (r & 3) + 8*(r >> 2) + 4*lhi;
                    h1_lds[row][col] = f2bf(silu_f(acc1[mt][nti][r] + bias));
                }
        }
    }

    // prefetch GEMM2 B(0), B(1) before the phase barrier (independent of h1)
    LDB2(0, bC);
    LDB2(1, bN);
    __syncthreads();

    // ---- phase 2: h2 = silu(h1 @ W2 + b2), fold (h2 . W3) into per-row energy ----
    auto LDA2 = [&](int kt, bf16x8* a) {
        #pragma unroll
        for (int mt = 0; mt < 2; ++mt)
            a[mt] = *reinterpret_cast<const bf16x8*>(
                &h1_lds[mt*32 + l31][kt*16 + (lhi << 3)]);
    };

    f32x16 acc[2][2];
    #pragma unroll
    for (int mt = 0; mt < 2; ++mt)
        #pragma unroll
        for (int nti = 0; nti < 2; ++nti)
            #pragma unroll
            for (int r = 0; r < 16; ++r) acc[mt][nti][r] = 0.0f;

    bf16x8 aC[2], aN[2];
    LDA2(0, aC);
    LDA2(1, aN);

    #pragma unroll 8
    for (int kt = 0; kt < KT2 - 2; ++kt) {
        bf16x8 aP[2], bP[2];
        LDB2(kt + 2, bP);
        LDA2(kt + 2, aP);
        #pragma unroll
        for (int nti = 0; nti < 2; ++nti)
            #pragma unroll
            for (int mt = 0; mt < 2; ++mt)
                acc[mt][nti] = mfma32(aC[mt], bC[nti], acc[mt][nti]);
        #pragma unroll
        for (int i = 0; i < 2; ++i) {
            aC[i] = aN[i]; aN[i] = aP[i];
            bC[i] = bN[i]; bN[i] = bP[i];
        }
    }
    // last two kt steps: no prefetch
    #pragma unroll
    for (int s = 0; s < 2; ++s) {
        #pragma unroll
        for (int nti = 0; nti < 2; ++nti)
            #pragma unroll
            for (int mt = 0; mt < 2; ++mt)
                acc[mt][nti] = mfma32(aC[mt], bC[nti], acc[mt][nti]);
        #pragma unroll
        for (int i = 0; i < 2; ++i) { aC[i] = aN[i]; bC[i] = bN[i]; }
    }

    // epilogue: silu + dot W3, accumulate per-row partials
    float e_lane[32];
    #pragma unroll
    for (int i = 0; i < 32; ++i) e_lane[i] = 0.0f;

    #pragma unroll
    for (int nti = 0; nti < 2; ++nti) {
        int col = w*64 + nti*32 + l31;
        float bias = b2[col];
        float w3v  = w3[col];
        #pragma unroll
        for (int mt = 0; mt < 2; ++mt)
            #pragma unroll
            for (int r = 0; r < 16; ++r) {
                float s = silu_f(acc[mt][nti][r] + bias);
                e_lane[mt*16 + r] += s * w3v;
            }
    }

    // reduce across the 32 column-lanes (xor offsets < 32 keep lhi halves intact)
    #pragma unroll
    for (int off = 1; off < 32; off <<= 1)
        #pragma unroll
        for (int i = 0; i < 32; ++i)
            e_lane[i] += __shfl_xor(e_lane[i], off, 64);

    if (l31 == 0) {
        #pragma unroll
        for (int mt = 0; mt < 2; ++mt)
            #pragma unroll
            for (int r = 0; r < 16; ++r) {
                int row = mt*32 + (r & 3) + 8*(r >> 2) + 4*lhi;
                e_red[w][row] = e_lane[mt*16 + r];
            }
    }
    __syncthreads();

    if (tid < BM) {
        float s = 0.0f;
        #pragma unroll
        for (int ww = 0; ww < 16; ++ww) s += e_red[ww][tid];
        node_e[row0 + tid] = s + b3[0];
    }
}

// ---------- deterministic segment sum over sorted batch ----------
__global__ void segsum(const float* __restrict__ node_e,
                       const int* __restrict__ batch,
                       float* __restrict__ out)
{
    int mol  = blockIdx.x;
    int lane = threadIdx.x;          // 64 threads

    int lo = 0, hi = NROWS;
    while (lo < hi) { int mid = (lo + hi) >> 1; if (batch[mid] < mol)     lo = mid + 1; else hi = mid; }
    int start = lo;
    lo = start; hi = NROWS;
    while (lo < hi) { int mid = (lo + hi) >> 1; if (batch[mid] < mol + 1) lo = mid + 1; else hi = mid; }
    int end = lo;

    float s = 0.0f;
    for (int i = start + lane; i < end; i += 64) s += node_e[i];
    #pragma unroll
    for (int off = 32; off; off >>= 1) s += __shfl_xor(s, off, 64);
    if (lane == 0) out[mol] = s;
}

// ---------- launch ----------
extern "C" void kernel_launch(void* const* d_in, const int* in_sizes, int n_in,
                              void* d_out, int out_size, void* d_ws, size_t ws_size,
                              hipStream_t stream) {
    const float* emb = (const float*)d_in[0];
    const float* W1  = (const float*)d_in[1];
    const float* b1  = (const float*)d_in[2];
    const float* W2  = (const float*)d_in[3];
    const float* b2  = (const float*)d_in[4];
    const float* W3  = (const float*)d_in[5];
    const float* b3  = (const float*)d_in[6];
    const int*   batch = (const int*)d_in[7];

    u16* w1f = (u16*)d_ws;                                        // 256 KB
    u16* w2f = (u16*)((char*)d_ws + (size_t)CIN * HDIM * 2);      // 2 MB
    float* node_e = (float*)((char*)d_ws + (size_t)CIN * HDIM * 2 + (size_t)HDIM * HDIM * 2);

    pack_w32<<<64,  256, 0, stream>>>(W1, w1f, CIN,  HDIM);
    pack_w32<<<512, 256, 0, stream>>>(W2, w2f, HDIM, HDIM);
    fused_mlp<<<NROWS / BM, 1024, 0, stream>>>(emb, w1f, w2f, b1, b2, W3, b3, node_e);
    segsum<<<NMOL, 64, 0, stream>>>(node_e, batch, (float*)d_out);
}

// Round 5
// 337.016 us; speedup vs baseline: 1.0921x; 1.0921x over previous
//
#include <hip/hip_runtime.h>

typedef unsigned short u16;
typedef __attribute__((ext_vector_type(8)))  short bf16x8;
typedef __attribute__((ext_vector_type(16))) float f32x16;

#define NROWS 131072
#define NMOL  2048
#define CIN   128
#define HDIM  1024
#define BM    64
#define EMBSTRIDE 1152   // 9*128

#define KT1 (CIN  / 16)   // 8
#define KT2 (HDIM / 16)   // 64
#define NT  (HDIM / 32)   // 32

// ---------- helpers ----------
__device__ __forceinline__ u16 f2bf(float f) {
    union { float f; unsigned u; } v; v.f = f;
    unsigned u = v.u;
    u += 0x7FFFu + ((u >> 16) & 1u);   // round-to-nearest-even
    return (u16)(u >> 16);
}

__device__ __forceinline__ float silu_f(float v) {
    float e = __expf(-v);
    return v * __builtin_amdgcn_rcpf(1.0f + e);
}

__device__ __forceinline__ f32x16 mfma32(bf16x8 a, bf16x8 b, f32x16 c) {
    return __builtin_amdgcn_mfma_f32_32x32x16_bf16(a, b, c, 0, 0, 0);
}

// ---------- pre-pass: pack W (K x N fp32 row-major) into bf16 32x32x16 B-fragments ----------
// frag id = kt*NT + nt. lane l, elem j -> W[kt*16 + (l>>5)*8 + j][nt*32 + (l&31)]
__global__ void pack_w32(const float* __restrict__ W, u16* __restrict__ dst, int K, int N) {
    int tid  = blockIdx.x * blockDim.x + threadIdx.x;
    int lane = tid & 63;
    int frag = tid >> 6;
    int NTl = N >> 5;
    int KTl = K >> 4;
    if (frag >= KTl * NTl) return;
    int kt = frag / NTl;
    int nt = frag - kt * NTl;
    int col  = (nt << 5) + (lane & 31);
    int krow = (kt << 4) + ((lane >> 5) << 3);
    __align__(16) u16 tmp[8];
    #pragma unroll
    for (int j = 0; j < 8; ++j) tmp[j] = f2bf(W[(size_t)(krow + j) * N + col]);
    *reinterpret_cast<uint4*>(dst + (size_t)tid * 8) = *reinterpret_cast<uint4*>(tmp);
}

// ---- asm issue of one step (2 kt) of B fragments: 8 x global_load_dwordx4 ----
// SGPR base = w2f (uniform kernel arg); all thread-varying terms live in the
// 32-bit VGPR voffsets vE (kt-even slice) and vO (kt-odd slice = vE + 32768).
#define ISSUE_B(buf, vE, vO)                                              \
  asm volatile(                                                           \
    "global_load_dwordx4 %0, %8, %10 offset:0\n\t"                        \
    "global_load_dwordx4 %1, %8, %10 offset:1024\n\t"                     \
    "global_load_dwordx4 %2, %8, %10 offset:2048\n\t"                     \
    "global_load_dwordx4 %3, %8, %10 offset:3072\n\t"                     \
    "global_load_dwordx4 %4, %9, %10 offset:0\n\t"                        \
    "global_load_dwordx4 %5, %9, %10 offset:1024\n\t"                     \
    "global_load_dwordx4 %6, %9, %10 offset:2048\n\t"                     \
    "global_load_dwordx4 %7, %9, %10 offset:3072"                         \
    : "=v"(buf[0]), "=v"(buf[1]), "=v"(buf[2]), "=v"(buf[3]),             \
      "=v"(buf[4]), "=v"(buf[5]), "=v"(buf[6]), "=v"(buf[7])              \
    : "v"(vE), "v"(vO), "s"(w2f)                                          \
    : "memory")

// ---- one kt half-step: 2 A LDS reads + 8 MFMAs from buf[OFS..OFS+3] ----
#define HALF_KT(buf, ktv, OFS)                                                             \
  {                                                                                        \
    const int _kt = (ktv);                                                                 \
    bf16x8 a0 = *reinterpret_cast<const bf16x8*>(&h1_lds[l31     ][_kt*16 + (lhi<<3)]);    \
    bf16x8 a1 = *reinterpret_cast<const bf16x8*>(&h1_lds[32 + l31][_kt*16 + (lhi<<3)]);    \
    acc[0][0] = mfma32(a0, buf[OFS+0], acc[0][0]);                                         \
    acc[1][0] = mfma32(a1, buf[OFS+0], acc[1][0]);                                         \
    acc[0][1] = mfma32(a0, buf[OFS+1], acc[0][1]);                                         \
    acc[1][1] = mfma32(a1, buf[OFS+1], acc[1][1]);                                         \
    acc[0][2] = mfma32(a0, buf[OFS+2], acc[0][2]);                                         \
    acc[1][2] = mfma32(a1, buf[OFS+2], acc[1][2]);                                         \
    acc[0][3] = mfma32(a0, buf[OFS+3], acc[0][3]);                                         \
    acc[1][3] = mfma32(a1, buf[OFS+3], acc[1][3]);                                         \
  }

// ---- one pipeline step: wait(N) -> 16 MFMA (setprio) -> optionally issue step s+2 ----
#define STEP(buf, sv, WAITN, DO_ISSUE)                                    \
  {                                                                       \
    const int _s = (sv);                                                  \
    asm volatile("s_waitcnt vmcnt(" #WAITN ")" ::: "memory");             \
    __builtin_amdgcn_sched_barrier(0);                                    \
    __builtin_amdgcn_s_setprio(1);                                        \
    HALF_KT(buf, 2*_s,     0)                                             \
    HALF_KT(buf, 2*_s + 1, 4)                                             \
    __builtin_amdgcn_s_setprio(0);                                        \
    if (DO_ISSUE) {                                                       \
      unsigned _vE = off0 + (unsigned)(_s + 2) * 65536u;                  \
      ISSUE_B(buf, _vE, _vE + 32768u);                                    \
    }                                                                     \
  }

// ---------- fused MLP : 512 threads = 8 waves ----------
// wave w covers output cols [w*128, w*128+128) = nt {4w..4w+3}; all 64 rows.
__global__ __launch_bounds__(512, 2) void fused_mlp(
    const float* __restrict__ emb,
    const u16*  __restrict__ w1f,
    const u16*  __restrict__ w2f,
    const float* __restrict__ b1,
    const float* __restrict__ b2,
    const float* __restrict__ w3,
    const float* __restrict__ b3,
    float* __restrict__ node_e)
{
    __shared__ u16  x_lds[BM][CIN + 8];      // 64 x 136 bf16 : 17.4 KB
    __shared__ u16  h1_lds[BM][HDIM + 8];    // 64 x 1032 bf16: 132 KB
    __shared__ float e_red[8][BM];           // 2 KB

    const int tid  = threadIdx.x;
    const int lane = tid & 63;
    const int w    = tid >> 6;               // wave 0..7
    const int l31  = lane & 31;
    const int lhi  = lane >> 5;              // 0/1
    const int row0 = blockIdx.x * BM;

    // ---- phase 0: stage x tile as bf16 ----
    {
        int r   = tid >> 3;                  // 0..63
        int seg = tid & 7;                   // 8 segs of 16 floats
        const float4* s4 = reinterpret_cast<const float4*>(
            emb + (size_t)(row0 + r) * EMBSTRIDE + seg * 16);
        __align__(16) u16 u[16];
        #pragma unroll
        for (int i = 0; i < 4; ++i) {
            float4 f = s4[i];
            u[i*4+0] = f2bf(f.x); u[i*4+1] = f2bf(f.y);
            u[i*4+2] = f2bf(f.z); u[i*4+3] = f2bf(f.w);
        }
        uint4* d = reinterpret_cast<uint4*>(&x_lds[r][seg * 16]);
        d[0] = reinterpret_cast<uint4*>(u)[0];
        d[1] = reinterpret_cast<uint4*>(u)[1];
    }

    // B-fragment loader for GEMM1 (compiler-managed): nt = 4w + nti
    auto LDB1 = [&](int kt, bf16x8* b) {
        #pragma unroll
        for (int nti = 0; nti < 4; ++nti)
            b[nti] = *reinterpret_cast<const bf16x8*>(
                w1f + (((size_t)kt * NT + 4 * w + nti) * 64 + lane) * 8);
    };

    bf16x8 bC[4], bN[4];
    LDB1(0, bC);
    __syncthreads();

    // ---- phase 1: h1 = silu(x @ W1 + b1) ----
    {
        f32x16 acc1[2][4];
        #pragma unroll
        for (int mt = 0; mt < 2; ++mt)
            #pragma unroll
            for (int nti = 0; nti < 4; ++nti)
                #pragma unroll
                for (int r = 0; r < 16; ++r) acc1[mt][nti][r] = 0.0f;

        #pragma unroll
        for (int kt = 0; kt < KT1; ++kt) {
            if (kt + 1 < KT1) LDB1(kt + 1, bN);
            bf16x8 a[2];
            #pragma unroll
            for (int mt = 0; mt < 2; ++mt)
                a[mt] = *reinterpret_cast<const bf16x8*>(
                    &x_lds[mt*32 + l31][kt*16 + (lhi << 3)]);
            #pragma unroll
            for (int nti = 0; nti < 4; ++nti)
                #pragma unroll
                for (int mt = 0; mt < 2; ++mt)
                    acc1[mt][nti] = mfma32(a[mt], bC[nti], acc1[mt][nti]);
            if (kt + 1 < KT1) {
                #pragma unroll
                for (int i = 0; i < 4; ++i) bC[i] = bN[i];
            }
        }

        // epilogue: silu -> bf16 -> h1_lds  (C/D: col=lane&31, row=(r&3)+8*(r>>2)+4*lhi)
        #pragma unroll
        for (int nti = 0; nti < 4; ++nti) {
            int col = w*128 + nti*32 + l31;
            float bias = b1[col];
            #pragma unroll
            for (int mt = 0; mt < 2; ++mt)
                #pragma unroll
                for (int r = 0; r < 16; ++r) {
                    int row = mt*32 + (r & 3) + 8*(r >> 2) + 4*lhi;
                    h1_lds[row][col] = f2bf(silu_f(acc1[mt][nti][r] + bias));
                }
        }
    }

    // ---- phase 2: hand-scheduled pipeline (T3/T4/T5), step = 2 kt ----
    // byte offset of fragment (kt, nt=4w+nti, lane): (kt*32 + 4w+nti)*1024 + lane*16
    const unsigned off0 = (unsigned)((w << 12) + (lane << 4));

    f32x16 acc[2][4];
    #pragma unroll
    for (int mt = 0; mt < 2; ++mt)
        #pragma unroll
        for (int nti = 0; nti < 4; ++nti)
            #pragma unroll
            for (int r = 0; r < 16; ++r) acc[mt][nti][r] = 0.0f;

    bf16x8 b0[8], b1v[8];
    // prologue: issue steps 0 and 1 (the barrier drains them; data ready at loop entry)
    ISSUE_B(b0,  off0,           off0 + 32768u);
    ISSUE_B(b1v, off0 + 65536u,  off0 + 98304u);
    __syncthreads();

    for (int s = 0; s < 30; s += 2) {
        STEP(b0,  s,     8, 1)
        STEP(b1v, s + 1, 8, 1)
    }
    STEP(b0,  30, 8, 0)
    STEP(b1v, 31, 0, 0)

    // epilogue: silu + dot W3, accumulate per-row partials
    float e_lane[32];
    #pragma unroll
    for (int i = 0; i < 32; ++i) e_lane[i] = 0.0f;

    #pragma unroll
    for (int nti = 0; nti < 4; ++nti) {
        int col = w*128 + nti*32 + l31;
        float bias = b2[col];
        float w3v  = w3[col];
        #pragma unroll
        for (int mt = 0; mt < 2; ++mt)
            #pragma unroll
            for (int r = 0; r < 16; ++r) {
                float s = silu_f(acc[mt][nti][r] + bias);
                e_lane[mt*16 + r] += s * w3v;
            }
    }

    // reduce across the 32 column-lanes (xor offsets < 32 keep lhi halves intact)
    #pragma unroll
    for (int off = 1; off < 32; off <<= 1)
        #pragma unroll
        for (int i = 0; i < 32; ++i)
            e_lane[i] += __shfl_xor(e_lane[i], off, 64);

    if (l31 == 0) {
        #pragma unroll
        for (int mt = 0; mt < 2; ++mt)
            #pragma unroll
            for (int r = 0; r < 16; ++r) {
                int row = mt*32 + (r & 3) + 8*(r >> 2) + 4*lhi;
                e_red[w][row] = e_lane[mt*16 + r];
            }
    }
    __syncthreads();

    if (tid < BM) {
        float s = 0.0f;
        #pragma unroll
        for (int ww = 0; ww < 8; ++ww) s += e_red[ww][tid];
        node_e[row0 + tid] = s + b3[0];
    }
}

// ---------- deterministic segment sum over sorted batch ----------
__global__ void segsum(const float* __restrict__ node_e,
                       const int* __restrict__ batch,
                       float* __restrict__ out)
{
    int mol  = blockIdx.x;
    int lane = threadIdx.x;          // 64 threads

    int lo = 0, hi = NROWS;
    while (lo < hi) { int mid = (lo + hi) >> 1; if (batch[mid] < mol)     lo = mid + 1; else hi = mid; }
    int start = lo;
    lo = start; hi = NROWS;
    while (lo < hi) { int mid = (lo + hi) >> 1; if (batch[mid] < mol + 1) lo = mid + 1; else hi = mid; }
    int end = lo;

    float s = 0.0f;
    for (int i = start + lane; i < end; i += 64) s += node_e[i];
    #pragma unroll
    for (int off = 32; off; off >>= 1) s += __shfl_xor(s, off, 64);
    if (lane == 0) out[mol] = s;
}

// ---------- launch ----------
extern "C" void kernel_launch(void* const* d_in, const int* in_sizes, int n_in,
                              void* d_out, int out_size, void* d_ws, size_t ws_size,
                              hipStream_t stream) {
    const float* emb = (const float*)d_in[0];
    const float* W1  = (const float*)d_in[1];
    const float* b1  = (const float*)d_in[2];
    const float* W2  = (const float*)d_in[3];
    const float* b2  = (const float*)d_in[4];
    const float* W3  = (const float*)d_in[5];
    const float* b3  = (const float*)d_in[6];
    const int*   batch = (const int*)d_in[7];

    u16* w1f = (u16*)d_ws;                                        // 256 KB
    u16* w2f = (u16*)((char*)d_ws + (size_t)CIN * HDIM * 2);      // 2 MB
    float* node_e = (float*)((char*)d_ws + (size_t)CIN * HDIM * 2 + (size_t)HDIM * HDIM * 2);

    pack_w32<<<64,  256, 0, stream>>>(W1, w1f, CIN,  HDIM);
    pack_w32<<<512, 256, 0, stream>>>(W2, w2f, HDIM, HDIM);
    fused_mlp<<<NROWS / BM, 512, 0, stream>>>(emb, w1f, w2f, b1, b2, W3, b3, node_e);
    segsum<<<NMOL, 64, 0, stream>>>(node_e, batch, (float*)d_out);
}